// Round 1
// 995.498 us; speedup vs baseline: 1.0178x; 1.0178x over previous
//
#include <hip/hip_runtime.h>
#include <stdint.h>
#include <stddef.h>

// GraphConvolution: out = relu( sum_s adj[s] @ (x @ W[s] + b[s]) )
// N=8192, S=3, D_IN=D_OUT=32.  adj (805 MB fp32) dominates -> HBM-bound,
// floor ~128 us at 6.3 TB/s.
//
// R0 analysis: dur_us 1013 = harness workspace-poison fill (~505 us, the
// 3 GiB fillBufferAligned dispatches at 80% HBM peak seen in rocprof) +
// pre (~5 us) + prop (~500 us).  prop achieves only 1.6 TB/s on adj.
// Theory: all 512 blocks stream the SAME 1 KB k-window in lockstep (same
// BW-limited rate, same chunk index) -> whole GPU hammers a small subset of
// HBM channels at any instant (32 KB row stride x shared window phase).
// Fix: per-block k-phase rotation of the chunk order (sum over chunks is
// order-independent) + A-prefetch depth 2 to cover inflated latency.

static constexpr int NN = 8192;
static constexpr int DD = 32;
static constexpr int SS = 3;
static constexpr int KB = 256;             // k-chunk staged per iteration
static constexpr int LSTR = KB + 8;        // LDS row stride (shorts)
static constexpr int NCH = SS * NN / KB;   // 96 chunks

typedef __attribute__((ext_vector_type(8))) short short8;   // 8 bf16 = 16 B
typedef __attribute__((ext_vector_type(4))) float floatx4;  // 16 B

__device__ __forceinline__ unsigned short f2bf(float f) {
  unsigned int u = __float_as_uint(f);
  u += 0x7FFFu + ((u >> 16) & 1u);
  return (unsigned short)(u >> 16);
}

__device__ __forceinline__ void barrier_no_vm_drain() {
  // __syncthreads() lowers with s_waitcnt vmcnt(0) before s_barrier,
  // draining the global prefetch queue. We only need LDS ordering.
  asm volatile("s_waitcnt lgkmcnt(0)\n\ts_barrier" ::: "memory");
}

// Kernel 1: preT[s][n][k] = (x @ W[s] + b[s])[k][n]  stored transposed, bf16.
extern "C" __global__ void __launch_bounds__(256)
pre_kernel(const float* __restrict__ x, const float* __restrict__ W,
           const float* __restrict__ b, unsigned short* __restrict__ preT) {
  __shared__ float xs[256 * 33];
  __shared__ float Ws[DD * DD];
  __shared__ float bs[DD];
  const int t = threadIdx.x;
  const int s = blockIdx.y;
  const int kbase = blockIdx.x * 256;

  #pragma unroll
  for (int j = 0; j < 32; ++j) {
    int idx = j * 256 + t;
    xs[(idx >> 5) * 33 + (idx & 31)] = x[kbase * DD + idx];
  }
  #pragma unroll
  for (int j = 0; j < 4; ++j) Ws[j * 256 + t] = W[s * DD * DD + j * 256 + t];
  if (t < DD) bs[t] = b[s * DD + t];
  __syncthreads();

  float xr[32];
  #pragma unroll
  for (int i = 0; i < 32; ++i) xr[i] = xs[t * 33 + i];

  unsigned short* o = preT + (size_t)s * DD * NN + kbase + t;
  #pragma unroll
  for (int n = 0; n < DD; ++n) {
    float acc = bs[n];
    #pragma unroll
    for (int i = 0; i < 32; ++i) acc += xr[i] * Ws[i * DD + n];
    o[(size_t)n * NN] = f2bf(acc);
  }
}

// Kernel 2: out[m][n] = relu( sum_s sum_k adj[s][m][k] * pre[s][k][n] )
// Block = 512 threads (8 waves), M-tile = 16 rows.  Per iteration: stage
// 16x256 fp32 of adj -> bf16 -> LDS; 8 waves each MFMA one 16x16x32 k-step.
// Chunk ORDER is rotated per block ((bid*37) mod 96) so the 512 blocks'
// HBM k-windows are decorrelated; A is prefetched 2 chunks ahead.
extern "C" __global__ void __launch_bounds__(512, 4)
prop_kernel(const float* __restrict__ adj, const unsigned short* __restrict__ preT,
            float* __restrict__ out) {
  const int tid  = threadIdx.x;
  const int wave = tid >> 6;
  const int lane = tid & 63;
  const int q = lane >> 4;   // 0..3
  const int c = lane & 15;   // 0..15
  const int m0 = blockIdx.x * 16;

  __shared__ unsigned short As[2][16 * LSTR];  // 16.9 KB
  __shared__ float red[8 * 512];               // 16 KB

  // Staging map: thread t loads 8 consecutive floats of row (t>>5), k-off (t&31)*8.
  const int srow  = tid >> 5;
  const int skoff = (tid & 31) * 8;
  const float* gA = adj + (size_t)(m0 + srow) * NN + skoff;

  // B fragment base: preT[c][wave*32 + q*8 ...] (16 B contiguous per lane, L2-resident)
  const unsigned short* gB = preT + (size_t)c * NN + wave * 32 + q * 8;

  floatx4 acc0 = {0.f, 0.f, 0.f, 0.f};
  floatx4 acc1 = {0.f, 0.f, 0.f, 0.f};

  // Per-block chunk-order rotation (37 coprime to 96).
  const int phase = (blockIdx.x * 37) % NCH;

  // chunk id: support s = id>>5, k-base kc = (id&31)*256
  auto a_addr = [&](int id) -> const float* {
    return gA + ((size_t)(id >> 5) << 26) + ((id & 31) << 8);
  };
  auto b_addr = [&](int id) -> const unsigned short* {
    return gB + ((size_t)(id >> 5) << 18) + ((id & 31) << 8);
  };

  // Prologue: A stages for iters 0 and 1, B stage for iter 0.
  floatx4 A0a, A0b, A1a, A1b;
  short8  Ba, Bb;
  {
    const float* p0 = a_addr(phase);
    A0a = *(const floatx4*)p0;
    A0b = *(const floatx4*)(p0 + 4);
    int id1 = phase + 1; if (id1 >= NCH) id1 -= NCH;
    const float* p1 = a_addr(id1);
    A1a = *(const floatx4*)p1;
    A1b = *(const floatx4*)(p1 + 4);
    const unsigned short* bp = b_addr(phase);
    Ba = *(const short8*)bp;
    Bb = *(const short8*)(bp + 16 * NN);
  }

  unsigned short* const dst0 = &As[0][srow * LSTR + skoff];
  unsigned short* const dst1 = &As[1][srow * LSTR + skoff];
  const unsigned short* const af0 = &As[0][c * LSTR + wave * 32 + q * 8];
  const unsigned short* const af1 = &As[1][c * LSTR + wave * 32 + q * 8];

  #pragma unroll 2
  for (int ch = 0; ch < NCH; ++ch) {
    // Prefetch A for iter ch+2, B for iter ch+1 (wrap: harmless reload).
    int i2 = ch + 2; if (i2 >= NCH) i2 -= NCH;
    i2 += phase;     if (i2 >= NCH) i2 -= NCH;
    int i1 = ch + 1; if (i1 >= NCH) i1 -= NCH;
    i1 += phase;     if (i1 >= NCH) i1 -= NCH;

    const float* pa = a_addr(i2);
    floatx4 NAa = *(const floatx4*)pa;
    floatx4 NAb = *(const floatx4*)(pa + 4);
    const unsigned short* pb = b_addr(i1);
    short8 NBa = *(const short8*)pb;
    short8 NBb = *(const short8*)(pb + 16 * NN);

    // Commit iter-ch chunk (loaded 2 iters ago) to LDS as bf16.
    short8 w;
    w[0] = (short)f2bf(A0a[0]); w[1] = (short)f2bf(A0a[1]);
    w[2] = (short)f2bf(A0a[2]); w[3] = (short)f2bf(A0a[3]);
    w[4] = (short)f2bf(A0b[0]); w[5] = (short)f2bf(A0b[1]);
    w[6] = (short)f2bf(A0b[2]); w[7] = (short)f2bf(A0b[3]);
    *(short8*)((ch & 1) ? dst1 : dst0) = w;

    barrier_no_vm_drain();  // prefetches stay in flight

    const short8 a = *(const short8*)((ch & 1) ? af1 : af0);
    acc0 = __builtin_amdgcn_mfma_f32_16x16x32_bf16(a, Ba, acc0, 0, 0, 0);
    acc1 = __builtin_amdgcn_mfma_f32_16x16x32_bf16(a, Bb, acc1, 0, 0, 0);

    // Shift pipeline stages.
    A0a = A1a; A0b = A1b; A1a = NAa; A1b = NAb;
    Ba = NBa;  Bb = NBb;
  }

  // Cross-wave reduction. C/D layout: row = q*4 + r, col = c.
  #pragma unroll
  for (int r = 0; r < 4; ++r) {
    red[wave * 512 + (q * 4 + r) * 32 + c]      = acc0[r];
    red[wave * 512 + (q * 4 + r) * 32 + 16 + c] = acc1[r];
  }
  __syncthreads();

  float v = 0.f;
  #pragma unroll
  for (int w2 = 0; w2 < 8; ++w2) v += red[w2 * 512 + tid];
  out[(size_t)m0 * DD + tid] = fmaxf(v, 0.f);
}

extern "C" void kernel_launch(void* const* d_in, const int* in_sizes, int n_in,
                              void* d_out, int out_size, void* d_ws, size_t ws_size,
                              hipStream_t stream) {
  const float* x   = (const float*)d_in[0];  // [8192, 32]
  const float* adj = (const float*)d_in[1];  // [3, 8192, 8192]
  const float* W   = (const float*)d_in[2];  // [3, 32, 32]
  const float* b   = (const float*)d_in[3];  // [3, 32]
  float* out = (float*)d_out;                // [8192, 32]
  unsigned short* preT = (unsigned short*)d_ws;  // [3][32][8192] bf16 = 1.5 MB

  dim3 g1(NN / 256, SS);
  pre_kernel<<<g1, 256, 0, stream>>>(x, W, b, preT);
  prop_kernel<<<NN / 16, 512, 0, stream>>>(adj, preT, out);
}